// Round 1
// 146.057 us; speedup vs baseline: 1.0596x; 1.0596x over previous
//
#include <hip/hip_runtime.h>
#include <math.h>

#define Bb 4
#define Hh 128
#define Ww 256
#define Cc 64
#define Ff 128
#define INH 130   // H+2
#define INW 258   // W+2

#define WSLOT 72   // shorts per column (64 + 8 pad): 144B stride, 16B-aligned
#define WCOLS 132  // cols 0..130 = data window, col 131 = dedicated zero column

typedef __attribute__((ext_vector_type(8))) __bf16 bf16x8;
typedef __attribute__((ext_vector_type(4))) float floatx4;

__device__ __forceinline__ unsigned short f2bf(float f) {
  unsigned int u = __float_as_uint(f);
  unsigned int r = u + 0x7fffu + ((u >> 16) & 1u);   // RNE
  return (unsigned short)(r >> 16);
}

// v_cvt_pk_bf16_f32: D[15:0]=bf16(S0), D[31:16]=bf16(S1), RNE — replaces
// ~10 VALU of manual round+pack with 1 instruction.
__device__ __forceinline__ unsigned int cvt_pk_bf16(float lo, float hi) {
  unsigned int r;
  asm("v_cvt_pk_bf16_f32 %0, %1, %2" : "=v"(r) : "v"(lo), "v"(hi));
  return r;
}

// ---------------------------------------------------------------------------
// Prep: kernel -> bf16 in MFMA-fragment order kTB[tap][kk][quad][f] (16B per
// (..,f) chunk -> B-frag loads are 16B/lane fully-coalesced, no LDS staging),
// + fp64 offset table (fp32 would flip the ux>0 branch at h=0).
// ---------------------------------------------------------------------------
__global__ void prep_kernel(const float* __restrict__ kmat,
                            float* __restrict__ offtab,
                            unsigned short* __restrict__ kTB) {
  int gid = blockIdx.x * 256 + threadIdx.x;
  if (gid < 576 * 128) {
    int f = gid & 127;
    int k = gid >> 7;
    int tap = k >> 6;
    int r = k & 63;
    int kk = r >> 5;
    int quad = (r >> 3) & 3;
    int i = r & 7;
    int chunk = tap * 8 + kk * 4 + quad;
    kTB[((size_t)chunk * 128 + f) * 8 + i] = f2bf(kmat[gid]);
  }
  if (gid < Hh * 9) {
    int h = gid / 9;
    int j = gid - h * 9;
    const double pi = 3.14159265358979323846;
    double unit_w = 2.0 * pi / (double)Ww;
    double unit_h = pi / (2.0 * (double)Hh);
    double rho = tan(unit_w);
    double theta = ((double)(Ww / 2) - 0.5 * (double)Ww) * unit_w;
    double phi = ((double)Hh - (double)h) * unit_h;
    double cph = cos(phi), sph = sin(phi);
    double cth = cos(theta), sth = sin(theta);
    double pux = cph * cth, puy = sph, puz = cph * sth;
    double txx = puz, txy = 0.0, txz = -pux;
    double tyx = puy * txz - puz * txy;
    double tyy = puz * txx - pux * txz;
    double tyz = pux * txy - puy * txx;
    const int r0t[9] = {1, 1, 1, 0, 0, 0, -1, -1, -1};
    const int r1t[9] = {-1, 0, 1, -1, 0, 1, -1, 0, 1};
    auto proj = [&](int r0, int r1, double& xr, double& yr) {
      double ux = pux + rho * ((double)r0 * txx + (double)r1 * tyx);
      double uy = puy + rho * ((double)r0 * txy + (double)r1 * tyy);
      double uz = puz + rho * ((double)r0 * txz + (double)r1 * tyz);
      double base = atan2(uz, ux);
      double th;
      if (ux > 0.0)        th = base;
      else if (ux < 0.0)   th = (uz >= 0.0) ? base + pi : base - pi;
      else                 th = (uz > 0.0) ? pi * 0.5 : -pi * 0.5;
      double ph = asin(uy);
      xr = (th / pi + 1.0) * 0.5 * (double)Ww;
      yr = (1.0 - 2.0 * ph / pi) * (double)Hh;
    };
    double xc, yc, xj, yj;
    proj(0, 0, xc, yc);
    proj(r0t[j], r1t[j], xj, yj);
    offtab[gid * 2 + 0] = (float)(xj - xc);   // added to y (faithful swap)
    offtab[gid * 2 + 1] = (float)(yj - yc);   // added to x
  }
}

// ---------------------------------------------------------------------------
// Fused: per (b,h,128-w tile). Per tap:
//  fill (8-channel tasks, cvt_pk packing) -> single barrier (double-buffered
//  window; a wave filling buf[t+2 & 1] has provably passed the barrier all
//  waves reach only after finishing MFMA(t) on the same buffer) -> MFMA with
//  A-frags from window, B-frags direct from coalesced global kTB (L1-hot;
//  kk=0 B-loads issued pre-barrier so the barrier's vmcnt(0) drain pays
//  their latency for free).
// ---------------------------------------------------------------------------
__global__ __launch_bounds__(256, 4) void fused_kernel(
    const float* __restrict__ in, const float* __restrict__ bias,
    const unsigned short* __restrict__ kTB, const float* __restrict__ offtab,
    float* __restrict__ out) {
  __shared__ unsigned short winH[2][WCOLS * WSLOT];

  // XCD swizzle: each XCD gets one b and a contiguous h-range (~4.4MB == L2)
  int lidx = ((blockIdx.x & 7) << 7) | (blockIdx.x >> 3);
  int wt = lidx & 1;
  int h  = (lidx >> 1) & 127;
  int b  = lidx >> 8;
  int w0 = wt << 7;

  int tid  = threadIdx.x;
  int lane = tid & 63;
  int wave = tid >> 6;
  int m_base = (wave >> 1) << 6;
  int n_base = (wave & 1) << 6;
  int l15  = lane & 15;
  int quad = lane >> 4;

  floatx4 acc[4][4];
#pragma unroll
  for (int i = 0; i < 4; i++)
#pragma unroll
    for (int j = 0; j < 4; j++) acc[i][j] = (floatx4){0.f, 0.f, 0.f, 0.f};

  const float* inb = in + (size_t)b * Hh * Ww * Cc;
  const bf16x8* kbase = (const bf16x8*)kTB;

  for (int tap = 0; tap < 9; tap++) {
    float off0 = offtab[(h * 9 + tap) * 2 + 0];
    float off1 = offtab[(h * 9 + tap) * 2 + 1];
    float dyk = (float)(tap / 3), dxk = (float)(tap % 3);

    // ---- y side (wave-uniform): rows + weights, pad folded into weights ----
    float y = (float)h + dyk + off0;
    y = fminf(fmaxf(y, 0.f), (float)(INH - 1));
    int y0i = (int)floorf(y);
    int y1i = y0i + 1;
    y0i = min(max(y0i, 0), INH - 1);
    y1i = min(max(y1i, 0), INH - 1);
    float wy0 = (float)y1i - y;
    float wy1 = y - (float)y0i;
    if (!(y0i >= 1 && y0i <= Hh)) wy0 = 0.f;
    if (!(y1i >= 1 && y1i <= Hh)) wy1 = 0.f;
    const float* row0 = inb + (size_t)min(max(y0i - 1, 0), Hh - 1) * Ww * Cc;
    const float* row1 = inb + (size_t)min(max(y1i - 1, 0), Hh - 1) * Ww * Cc;

    // ---- x side: block-uniform fractional weights + window base ----
    float xrep = (float)w0 + dxk + off1;
    float flo  = floorf(xrep);
    int jb = (int)flo - 1;
    float fr = xrep - flo;              // uniform frac across w (±1ulp, benign)
    float q00 = wy0 * (1.f - fr), q01 = wy0 * fr;
    float q10 = wy1 * (1.f - fr), q11 = wy1 * fr;

    // ---- per-lane slots for this tap ----
    int slotv[4];
#pragma unroll
    for (int mi = 0; mi < 4; mi++) {
      int w = m_base + mi * 16 + l15;
      float x = (float)(w0 + w) + dxk + off1;   // ref op order
      if (x < 0.f) x += (float)INW;
      if (x > (float)(INW - 1)) x -= (float)INW;
      int x0i = (int)floorf(x);
      int s = x0i - jb;
      if (s < 0) s += INW;      // single-wrap lanes -> mod lookup
      if (s > 131) s = 131;     // anything else -> zero column
      slotv[mi] = s;
    }

    unsigned short* win = winH[tap & 1];

    // ---- fill: 132 cols x 8 ch-groups (8 ch/task); per-col overhead paid
    //      once per 8 elements; packing via v_cvt_pk_bf16_f32 ----
    for (int it = 0; it < 5; it++) {
      int task = tid + (it << 8);
      if (task < WCOLS * 8) {
        int j  = task >> 3;
        int c8 = (task & 7) << 3;
        int col = jb + j;
        if (col < 0) col += INW;
        if (col > INW - 1) col -= INW;
        int ncol = jb + j + 1;
        if (ncol < 0) ncol += INW;
        if (ncol > INW - 1) ncol -= INW;
        bool cok = (col >= 1) & (col <= Ww) & (j < 131);
        bool nok = (ncol >= 1) & (ncol <= Ww) & (j < 131);
        int ci = min(max(col - 1, 0), Ww - 1);
        int ni = min(max(ncol - 1, 0), Ww - 1);
        float m0 = cok ? 1.f : 0.f, m1 = nok ? 1.f : 0.f;
        float w00 = q00 * m0, w01 = q01 * m1, w10 = q10 * m0, w11 = q11 * m1;
        const float* pa = row0 + ci * Cc + c8;
        const float* pb = row0 + ni * Cc + c8;
        const float* pc = row1 + ci * Cc + c8;
        const float* pd = row1 + ni * Cc + c8;
        uint4 st;
        {
          float4 a0 = *(const float4*)pa;
          float4 a1 = *(const float4*)pb;
          float4 b0 = *(const float4*)pc;
          float4 b1 = *(const float4*)pd;
          float px = w00 * a0.x + w01 * a1.x + w10 * b0.x + w11 * b1.x;
          float py = w00 * a0.y + w01 * a1.y + w10 * b0.y + w11 * b1.y;
          float pz = w00 * a0.z + w01 * a1.z + w10 * b0.z + w11 * b1.z;
          float pw = w00 * a0.w + w01 * a1.w + w10 * b0.w + w11 * b1.w;
          st.x = cvt_pk_bf16(px, py);
          st.y = cvt_pk_bf16(pz, pw);
        }
        {
          float4 a0 = *(const float4*)(pa + 4);
          float4 a1 = *(const float4*)(pb + 4);
          float4 b0 = *(const float4*)(pc + 4);
          float4 b1 = *(const float4*)(pd + 4);
          float px = w00 * a0.x + w01 * a1.x + w10 * b0.x + w11 * b1.x;
          float py = w00 * a0.y + w01 * a1.y + w10 * b0.y + w11 * b1.y;
          float pz = w00 * a0.z + w01 * a1.z + w10 * b0.z + w11 * b1.z;
          float pw = w00 * a0.w + w01 * a1.w + w10 * b0.w + w11 * b1.w;
          st.z = cvt_pk_bf16(px, py);
          st.w = cvt_pk_bf16(pz, pw);
        }
        *(uint4*)(&win[j * WSLOT + c8]) = st;   // 16B-aligned ds_write_b128
      }
    }

    // ---- B-frags kk=0 issued pre-barrier: barrier's vmcnt(0) drain
    //      completes them; data ready at first MFMA ----
    int ch0 = (tap * 8 + quad) * 128;
    bf16x8 bfrag0[4];
#pragma unroll
    for (int v = 0; v < 4; v++)
      bfrag0[v] = kbase[ch0 + n_base + v * 16 + l15];

    __syncthreads();

    // ---- MFMA: A-frags = raw ds_read_b128 from the premixed window ----
    bf16x8 af[4];
#pragma unroll
    for (int mi = 0; mi < 4; mi++)
      af[mi] = *(const bf16x8*)&win[slotv[mi] * WSLOT + quad * 8];
    bf16x8 bfrag1[4];
#pragma unroll
    for (int v = 0; v < 4; v++)
      bfrag1[v] = kbase[ch0 + 4 * 128 + n_base + v * 16 + l15];
#pragma unroll
    for (int mi = 0; mi < 4; mi++)
#pragma unroll
      for (int v = 0; v < 4; v++)
        acc[mi][v] = __builtin_amdgcn_mfma_f32_16x16x32_bf16(
            af[mi], bfrag0[v], acc[mi][v], 0, 0, 0);
#pragma unroll
    for (int mi = 0; mi < 4; mi++)
      af[mi] = *(const bf16x8*)&win[slotv[mi] * WSLOT + 32 + quad * 8];
#pragma unroll
    for (int mi = 0; mi < 4; mi++)
#pragma unroll
      for (int v = 0; v < 4; v++)
        acc[mi][v] = __builtin_amdgcn_mfma_f32_16x16x32_bf16(
            af[mi], bfrag1[v], acc[mi][v], 0, 0, 0);
    // no trailing barrier: next tap fills the other buffer; double-buffer
    // ordering proof in header comment
  }

  // ---- epilogue: bias + relu (C/D: col=lane&15, row=quad*4+r) ----
  size_t outbase = ((size_t)(b * Hh + h) * Ww + w0);
#pragma unroll
  for (int ni = 0; ni < 4; ni++) {
    int f = n_base + ni * 16 + l15;
    float bv = bias[f];
#pragma unroll
    for (int mi = 0; mi < 4; mi++) {
#pragma unroll
      for (int r = 0; r < 4; r++) {
        int m = m_base + mi * 16 + quad * 4 + r;
        out[(outbase + m) * Ff + f] = fmaxf(acc[mi][ni][r] + bv, 0.f);
      }
    }
  }
}

extern "C" void kernel_launch(void* const* d_in, const int* in_sizes, int n_in,
                              void* d_out, int out_size, void* d_ws, size_t ws_size,
                              hipStream_t stream) {
  const float* in   = (const float*)d_in[0];
  const float* kmat = (const float*)d_in[1];
  const float* bias = (const float*)d_in[2];
  float* out = (float*)d_out;

  float* offtab = (float*)d_ws;
  unsigned short* kTB = (unsigned short*)((char*)d_ws + Hh * 9 * 2 * sizeof(float));
  if (ws_size < (size_t)(Hh * 9 * 2 * sizeof(float) + 128 * 576 * sizeof(unsigned short)))
    return;

  prep_kernel<<<288, 256, 0, stream>>>(kmat, offtab, kTB);
  fused_kernel<<<Bb * Hh * (Ww / 128), 256, 0, stream>>>(in, bias, kTB, offtab, out);
}

// Round 2
// 144.768 us; speedup vs baseline: 1.0691x; 1.0089x over previous
//
#include <hip/hip_runtime.h>
#include <math.h>

#define Bb 4
#define Hh 128
#define Ww 256
#define Cc 64
#define Ff 128
#define INH 130   // H+2
#define INW 258   // W+2

#define WSLOT 72   // shorts per column (64 + 8 pad): 144B stride, 16B-aligned
#define WCOLS 132  // cols 0..130 = data window, col 131 = dedicated zero column

typedef __attribute__((ext_vector_type(8))) __bf16 bf16x8;
typedef __attribute__((ext_vector_type(4))) float floatx4;

__device__ __forceinline__ unsigned short f2bf(float f) {
  unsigned int u = __float_as_uint(f);
  unsigned int r = u + 0x7fffu + ((u >> 16) & 1u);   // RNE
  return (unsigned short)(r >> 16);
}

// v_cvt_pk_bf16_f32: D[15:0]=bf16(S0), D[31:16]=bf16(S1), RNE.
__device__ __forceinline__ unsigned int cvt_pk_bf16(float lo, float hi) {
  unsigned int r;
  asm("v_cvt_pk_bf16_f32 %0, %1, %2" : "=v"(r) : "v"(lo), "v"(hi));
  return r;
}

// Block-uniform values are data-derived (offtab loads) so the compiler can't
// prove uniformity; force them into SGPRs so fill loads get saddr form
// (SGPR base + 32-bit voffset) instead of per-task 64-bit VGPR addr chains.
__device__ __forceinline__ float rfl_f(float x) {
  return __int_as_float(__builtin_amdgcn_readfirstlane(__float_as_int(x)));
}
__device__ __forceinline__ int rfl_i(int x) {
  return __builtin_amdgcn_readfirstlane(x);
}
__device__ __forceinline__ const float* rfl_p(const float* p) {
  unsigned long long u = (unsigned long long)p;
  unsigned lo = (unsigned)__builtin_amdgcn_readfirstlane((int)(unsigned)u);
  unsigned hi = (unsigned)__builtin_amdgcn_readfirstlane((int)(unsigned)(u >> 32));
  return (const float*)(((unsigned long long)hi << 32) | lo);
}

// ---------------------------------------------------------------------------
// Prep: kernel -> bf16 in MFMA-fragment order kTB[tap][kk][quad][f] (16B per
// (..,f) chunk -> B-frag loads are 16B/lane fully-coalesced, no LDS staging),
// + fp64 offset table (fp32 would flip the ux>0 branch at h=0).
// ---------------------------------------------------------------------------
__global__ void prep_kernel(const float* __restrict__ kmat,
                            float* __restrict__ offtab,
                            unsigned short* __restrict__ kTB) {
  int gid = blockIdx.x * 256 + threadIdx.x;
  if (gid < 576 * 128) {
    int f = gid & 127;
    int k = gid >> 7;
    int tap = k >> 6;
    int r = k & 63;
    int kk = r >> 5;
    int quad = (r >> 3) & 3;
    int i = r & 7;
    int chunk = tap * 8 + kk * 4 + quad;
    kTB[((size_t)chunk * 128 + f) * 8 + i] = f2bf(kmat[gid]);
  }
  if (gid < Hh * 9) {
    int h = gid / 9;
    int j = gid - h * 9;
    const double pi = 3.14159265358979323846;
    double unit_w = 2.0 * pi / (double)Ww;
    double unit_h = pi / (2.0 * (double)Hh);
    double rho = tan(unit_w);
    double theta = ((double)(Ww / 2) - 0.5 * (double)Ww) * unit_w;
    double phi = ((double)Hh - (double)h) * unit_h;
    double cph = cos(phi), sph = sin(phi);
    double cth = cos(theta), sth = sin(theta);
    double pux = cph * cth, puy = sph, puz = cph * sth;
    double txx = puz, txy = 0.0, txz = -pux;
    double tyx = puy * txz - puz * txy;
    double tyy = puz * txx - pux * txz;
    double tyz = pux * txy - puy * txx;
    const int r0t[9] = {1, 1, 1, 0, 0, 0, -1, -1, -1};
    const int r1t[9] = {-1, 0, 1, -1, 0, 1, -1, 0, 1};
    auto proj = [&](int r0, int r1, double& xr, double& yr) {
      double ux = pux + rho * ((double)r0 * txx + (double)r1 * tyx);
      double uy = puy + rho * ((double)r0 * txy + (double)r1 * tyy);
      double uz = puz + rho * ((double)r0 * txz + (double)r1 * tyz);
      double base = atan2(uz, ux);
      double th;
      if (ux > 0.0)        th = base;
      else if (ux < 0.0)   th = (uz >= 0.0) ? base + pi : base - pi;
      else                 th = (uz > 0.0) ? pi * 0.5 : -pi * 0.5;
      double ph = asin(uy);
      xr = (th / pi + 1.0) * 0.5 * (double)Ww;
      yr = (1.0 - 2.0 * ph / pi) * (double)Hh;
    };
    double xc, yc, xj, yj;
    proj(0, 0, xc, yc);
    proj(r0t[j], r1t[j], xj, yj);
    offtab[gid * 2 + 0] = (float)(xj - xc);   // added to y (faithful swap)
    offtab[gid * 2 + 1] = (float)(yj - yc);   // added to x
  }
}

// ---------------------------------------------------------------------------
// Fused: per (b,h,128-w tile). Per tap: fill premixed window (8-ch tasks,
// saddr-form loads, cvt_pk packing) -> single barrier (double-buffered
// window; all waves passed barrier(t) => all finished MFMA(t-1) on the
// other buffer) -> MFMA with A-frags from window, B-frags direct from
// coalesced global kTB (kk=0 loads issued pre-barrier: the barrier's
// vmcnt(0) drain completes them for free).
// ---------------------------------------------------------------------------
__global__ __launch_bounds__(256, 4) void fused_kernel(
    const float* __restrict__ in, const float* __restrict__ bias,
    const unsigned short* __restrict__ kTB, const float* __restrict__ offtab,
    float* __restrict__ out) {
  __shared__ unsigned short winH[2][WCOLS * WSLOT];

  // XCD swizzle: each XCD gets one b and a contiguous h-range (~4.4MB == L2)
  int lidx = ((blockIdx.x & 7) << 7) | (blockIdx.x >> 3);
  int wt = lidx & 1;
  int h  = (lidx >> 1) & 127;
  int b  = lidx >> 8;
  int w0 = wt << 7;

  int tid  = threadIdx.x;
  int lane = tid & 63;
  int wave = tid >> 6;
  int m_base = (wave >> 1) << 6;
  int n_base = (wave & 1) << 6;
  int l15  = lane & 15;
  int quad = lane >> 4;

  floatx4 acc[4][4];
#pragma unroll
  for (int i = 0; i < 4; i++)
#pragma unroll
    for (int j = 0; j < 4; j++) acc[i][j] = (floatx4){0.f, 0.f, 0.f, 0.f};

  const float* inb = in + (size_t)b * Hh * Ww * Cc;
  const bf16x8* kbase = (const bf16x8*)kTB;

  for (int tap = 0; tap < 9; tap++) {
    float off0 = offtab[(h * 9 + tap) * 2 + 0];
    float off1 = offtab[(h * 9 + tap) * 2 + 1];
    float dyk = (float)(tap / 3), dxk = (float)(tap % 3);

    // ---- y side (wave-uniform): rows + weights, pad folded into weights ----
    float y = (float)h + dyk + off0;
    y = fminf(fmaxf(y, 0.f), (float)(INH - 1));
    int y0i = (int)floorf(y);
    int y1i = y0i + 1;
    y0i = min(max(y0i, 0), INH - 1);
    y1i = min(max(y1i, 0), INH - 1);
    float wy0 = (float)y1i - y;
    float wy1 = y - (float)y0i;
    if (!(y0i >= 1 && y0i <= Hh)) wy0 = 0.f;
    if (!(y1i >= 1 && y1i <= Hh)) wy1 = 0.f;
    const float* row0 = rfl_p(inb + (size_t)min(max(y0i - 1, 0), Hh - 1) * Ww * Cc);
    const float* row1 = rfl_p(inb + (size_t)min(max(y1i - 1, 0), Hh - 1) * Ww * Cc);

    // ---- x side: block-uniform fractional weights + window base ----
    float xrep = (float)w0 + dxk + off1;
    float flo  = floorf(xrep);
    int jb = rfl_i((int)flo - 1);
    float fr = xrep - flo;              // uniform frac across w (±1ulp, benign)
    float q00 = rfl_f(wy0 * (1.f - fr)), q01 = rfl_f(wy0 * fr);
    float q10 = rfl_f(wy1 * (1.f - fr)), q11 = rfl_f(wy1 * fr);

    // ---- per-lane slots for this tap ----
    int slotv[4];
#pragma unroll
    for (int mi = 0; mi < 4; mi++) {
      int w = m_base + mi * 16 + l15;
      float x = (float)(w0 + w) + dxk + off1;   // ref op order
      if (x < 0.f) x += (float)INW;
      if (x > (float)(INW - 1)) x -= (float)INW;
      int x0i = (int)floorf(x);
      int s = x0i - jb;
      if (s < 0) s += INW;      // single-wrap lanes -> mod lookup
      if (s > 131) s = 131;     // anything else -> zero column
      slotv[mi] = s;
    }

    unsigned short* win = winH[tap & 1];
    const char* r0 = (const char*)row0;
    const char* r1 = (const char*)row1;

    // ---- fill: 132 cols x 8 ch-groups; saddr loads, cndmask weights ----
    for (int it = 0; it < 5; it++) {
      int task = tid + (it << 8);
      if (task < WCOLS * 8) {
        int j  = task >> 3;
        int c8 = (task & 7) << 3;
        int col = jb + j;                       // jb in SGPR
        if (col < 0) col += INW;
        if (col > INW - 1) col -= INW;          // col in [0,257]
        int ncol = (col == INW - 1) ? 0 : col + 1;   // == wrap(raw col+1)
        bool jok = (j < WCOLS - 1);
        bool cok = ((unsigned)(col - 1) < (unsigned)Ww) & jok;
        bool nok = ((unsigned)(ncol - 1) < (unsigned)Ww) & jok;
        // masked lanes: address is garbage-but-in-bounds, weight is 0
        unsigned offc = (((unsigned)((col - 1) & (Ww - 1))) << 8) + ((unsigned)c8 << 2);
        unsigned offn = (((unsigned)((ncol - 1) & (Ww - 1))) << 8) + ((unsigned)c8 << 2);
        float w00 = cok ? q00 : 0.f;
        float w01 = nok ? q01 : 0.f;
        float w10 = cok ? q10 : 0.f;
        float w11 = nok ? q11 : 0.f;
        uint4 st;
        {
          float4 a0 = *(const float4*)(r0 + offc);
          float4 a1 = *(const float4*)(r0 + offn);
          float4 b0 = *(const float4*)(r1 + offc);
          float4 b1 = *(const float4*)(r1 + offn);
          float px = w00 * a0.x + w01 * a1.x + w10 * b0.x + w11 * b1.x;
          float py = w00 * a0.y + w01 * a1.y + w10 * b0.y + w11 * b1.y;
          float pz = w00 * a0.z + w01 * a1.z + w10 * b0.z + w11 * b1.z;
          float pw = w00 * a0.w + w01 * a1.w + w10 * b0.w + w11 * b1.w;
          st.x = cvt_pk_bf16(px, py);
          st.y = cvt_pk_bf16(pz, pw);
        }
        {
          float4 a0 = *(const float4*)(r0 + offc + 16);
          float4 a1 = *(const float4*)(r0 + offn + 16);
          float4 b0 = *(const float4*)(r1 + offc + 16);
          float4 b1 = *(const float4*)(r1 + offn + 16);
          float px = w00 * a0.x + w01 * a1.x + w10 * b0.x + w11 * b1.x;
          float py = w00 * a0.y + w01 * a1.y + w10 * b0.y + w11 * b1.y;
          float pz = w00 * a0.z + w01 * a1.z + w10 * b0.z + w11 * b1.z;
          float pw = w00 * a0.w + w01 * a1.w + w10 * b0.w + w11 * b1.w;
          st.z = cvt_pk_bf16(px, py);
          st.w = cvt_pk_bf16(pz, pw);
        }
        *(uint4*)(&win[j * WSLOT + c8]) = st;   // 16B-aligned ds_write_b128
      }
    }

    // ---- B-frags kk=0 issued pre-barrier: barrier's vmcnt(0) drain
    //      completes them; data ready at first MFMA ----
    int ch0 = (tap * 8 + quad) * 128;
    bf16x8 bfrag0[4];
#pragma unroll
    for (int v = 0; v < 4; v++)
      bfrag0[v] = kbase[ch0 + n_base + v * 16 + l15];

    __syncthreads();

    // ---- MFMA: A-frags = raw ds_read_b128 from the premixed window ----
    bf16x8 af[4];
#pragma unroll
    for (int mi = 0; mi < 4; mi++)
      af[mi] = *(const bf16x8*)&win[slotv[mi] * WSLOT + quad * 8];
    bf16x8 bfrag1[4];
#pragma unroll
    for (int v = 0; v < 4; v++)
      bfrag1[v] = kbase[ch0 + 4 * 128 + n_base + v * 16 + l15];
#pragma unroll
    for (int mi = 0; mi < 4; mi++)
#pragma unroll
      for (int v = 0; v < 4; v++)
        acc[mi][v] = __builtin_amdgcn_mfma_f32_16x16x32_bf16(
            af[mi], bfrag0[v], acc[mi][v], 0, 0, 0);
#pragma unroll
    for (int mi = 0; mi < 4; mi++)
      af[mi] = *(const bf16x8*)&win[slotv[mi] * WSLOT + 32 + quad * 8];
#pragma unroll
    for (int mi = 0; mi < 4; mi++)
#pragma unroll
      for (int v = 0; v < 4; v++)
        acc[mi][v] = __builtin_amdgcn_mfma_f32_16x16x32_bf16(
            af[mi], bfrag1[v], acc[mi][v], 0, 0, 0);
    // no trailing barrier: next tap fills the other buffer (proof above)
  }

  // ---- epilogue: bias + relu (C/D: col=lane&15, row=quad*4+r) ----
  size_t outbase = ((size_t)(b * Hh + h) * Ww + w0);
#pragma unroll
  for (int ni = 0; ni < 4; ni++) {
    int f = n_base + ni * 16 + l15;
    float bv = bias[f];
#pragma unroll
    for (int mi = 0; mi < 4; mi++) {
#pragma unroll
      for (int r = 0; r < 4; r++) {
        int m = m_base + mi * 16 + quad * 4 + r;
        out[(outbase + m) * Ff + f] = fmaxf(acc[mi][ni][r] + bv, 0.f);
      }
    }
  }
}

extern "C" void kernel_launch(void* const* d_in, const int* in_sizes, int n_in,
                              void* d_out, int out_size, void* d_ws, size_t ws_size,
                              hipStream_t stream) {
  const float* in   = (const float*)d_in[0];
  const float* kmat = (const float*)d_in[1];
  const float* bias = (const float*)d_in[2];
  float* out = (float*)d_out;

  float* offtab = (float*)d_ws;
  unsigned short* kTB = (unsigned short*)((char*)d_ws + Hh * 9 * 2 * sizeof(float));
  if (ws_size < (size_t)(Hh * 9 * 2 * sizeof(float) + 128 * 576 * sizeof(unsigned short)))
    return;

  prep_kernel<<<288, 256, 0, stream>>>(kmat, offtab, kTB);
  fused_kernel<<<Bb * Hh * (Ww / 128), 256, 0, stream>>>(in, bias, kTB, offtab, out);
}